// Round 3
// baseline (1707.407 us; speedup 1.0000x reference)
//
#include <hip/hip_runtime.h>
#include <stdint.h>

#define NN 50000      // nodes
#define NRELS 3       // relations
#define NE 800000     // edges per relation
#define DIN 300
#define DH 256
#define NBUK 196      // ceil(NN/256) row-buckets per CSR set
#define NBT (6*NBUK)  // 1176 buckets total
#define PAD 16        // ints per bucket counter (one 64B line)
#define MAXB 6144     // LDS edge-staging capacity per bucket

typedef __attribute__((ext_vector_type(8))) short bf16x8;
typedef __attribute__((ext_vector_type(4))) float f32x4;

__device__ __forceinline__ float bf2f(unsigned short u){
    union { unsigned int i; float f; } v; v.i = ((unsigned int)u) << 16; return v.f;
}
__device__ __forceinline__ unsigned short f2bf(float f){
    union { float f; unsigned int i; } v; v.f = f;
    return (unsigned short)((v.i + 0x7FFFu + ((v.i >> 16) & 1u)) >> 16);
}

// ---------------- attention softmax (6 scalars) ----------------
__global__ void k_att(const float* __restrict__ a_att, const float* __restrict__ r_att,
                      float* __restrict__ att){
    if (threadIdx.x == 0){
        float m = fmaxf(a_att[0], fmaxf(a_att[1], a_att[2]));
        float e0 = expf(a_att[0]-m), e1 = expf(a_att[1]-m), e2 = expf(a_att[2]-m);
        float s = e0+e1+e2;
        att[0]=e0/s; att[1]=e1/s; att[2]=e2/s;
        m = fmaxf(r_att[0], fmaxf(r_att[1], r_att[2]));
        e0 = expf(r_att[0]-m); e1 = expf(r_att[1]-m); e2 = expf(r_att[2]-m);
        s = e0+e1+e2;
        att[3]=e0/s; att[4]=e1/s; att[5]=e2/s;
    }
}

// ---------------- bucket histogram ----------------
__global__ void k_bhist(const int* __restrict__ src, const int* __restrict__ dst,
                        int* __restrict__ bcount){
    int rel = blockIdx.y;
    int e = blockIdx.x*256 + threadIdx.x;
    if (e >= NE) return;
    int s = src[(size_t)rel*NE + e];
    int d = dst[(size_t)rel*NE + e];
    atomicAdd(&bcount[(rel*NBUK + (d >> 8))*PAD], 1);        // layer1: row=dst
    atomicAdd(&bcount[((NRELS+rel)*NBUK + (s >> 8))*PAD], 1);// layer2: row=src
}

// ---------------- bucket scan (one block); counters become cursors ----------------
__global__ void k_bscan(int* __restrict__ bcount, int* __restrict__ bucket_base){
    __shared__ int v[1216];
    int tid = threadIdx.x;
    for (int i = tid; i < 1216; i += 256) v[i] = (i < NBT) ? bcount[i*PAD] : 0;
    __syncthreads();
    if (tid < 64){
        int base = tid*19;
        int s = 0;
        #pragma unroll
        for (int j = 0; j < 19; ++j){ int t = v[base+j]; v[base+j] = s; s += t; }
        int run = s;
        #pragma unroll
        for (int off_ = 1; off_ < 64; off_ <<= 1){
            int t = __shfl_up(run, off_);
            if (tid >= off_) run += t;
        }
        int excl = run - s;
        #pragma unroll
        for (int j = 0; j < 19; ++j) v[base+j] += excl;
    }
    __syncthreads();
    for (int i = tid; i < NBT; i += 256){
        bucket_base[i] = v[i];
        bcount[i*PAD] = v[i];      // cursor = global base
    }
    if (tid == 0) bucket_base[NBT] = 6*NE;
}

// ---------------- bucketed scatter: 4B packed (row_local<<16 | col) ----------------
__global__ void k_bscatter(const int* __restrict__ src, const int* __restrict__ dst,
                           int* __restrict__ bcur, unsigned int* __restrict__ bucketbuf){
    int rel = blockIdx.y;
    int e = blockIdx.x*256 + threadIdx.x;
    if (e >= NE) return;
    int s = src[(size_t)rel*NE + e];
    int d = dst[(size_t)rel*NE + e];
    {   // layer1: row=dst, col=src
        int slot = atomicAdd(&bcur[(rel*NBUK + (d >> 8))*PAD], 1);
        bucketbuf[slot] = ((unsigned)(d & 255) << 16) | (unsigned)s;
    }
    {   // layer2: row=src, col=dst
        int slot = atomicAdd(&bcur[((NRELS+rel)*NBUK + (s >> 8))*PAD], 1);
        bucketbuf[slot] = ((unsigned)(s & 255) << 16) | (unsigned)d;
    }
}

// ---------------- per-bucket finalize: row_start + sorted colS ----------------
__global__ __launch_bounds__(256) void k_bfinal(const unsigned int* __restrict__ bucketbuf,
                                                const int* __restrict__ bucket_base,
                                                int* __restrict__ row_start,
                                                unsigned short* __restrict__ colS){
    __shared__ int lhist[256];
    __shared__ int lcur[256];
    __shared__ unsigned int ledge[MAXB];
    int b = blockIdx.x;
    int a = b / NBUK, bu = b % NBUK;
    int row0 = bu << 8;
    int base = bucket_base[b], end = bucket_base[b+1];
    int cnt = end - base;
    int tid = threadIdx.x;
    lhist[tid] = 0;
    __syncthreads();
    bool staged = (cnt <= MAXB);
    for (int i = tid; i < cnt; i += 256){
        unsigned int p = bucketbuf[base + i];
        if (staged) ledge[i] = p;
        atomicAdd(&lhist[p >> 16], 1);
    }
    __syncthreads();
    // exclusive scan of lhist (Hillis-Steele, in place)
    int v = lhist[tid];
    for (int off_ = 1; off_ < 256; off_ <<= 1){
        int t = (tid >= off_) ? lhist[tid - off_] : 0;
        __syncthreads();
        lhist[tid] += t;
        __syncthreads();
    }
    int excl = lhist[tid] - v;
    lcur[tid] = excl;
    int rows = NN - row0; if (rows > 256) rows = 256;
    if (tid < rows) row_start[a*(NN+1) + row0 + tid] = base + excl;  // global colS offset
    if (bu == NBUK-1 && tid == 0) row_start[a*(NN+1) + NN] = (a+1)*NE;
    __syncthreads();
    for (int i = tid; i < cnt; i += 256){
        unsigned int p = staged ? ledge[i] : bucketbuf[base + i];
        int rl = (int)(p >> 16);
        int pos = atomicAdd(&lcur[rl], 1);
        colS[base + pos] = (unsigned short)(p & 0xFFFFu);
    }
}

// ---------------- GEMM1: f32 VALU, out[m][n] = A@W + b, bf16 out ----------------
template<int K, int BK>
__global__ __launch_bounds__(256) void k_gemm(const float* __restrict__ A,
                                              const float* __restrict__ W,
                                              const float* __restrict__ bias,
                                              unsigned short* __restrict__ out, int M){
    constexpr int BM = 32;
    __shared__ float ldsW[BK*DH];
    __shared__ float ldsX[BM*BK];
    const int tid = threadIdx.x;
    const int row0 = blockIdx.x * BM;
    const int jc = tid & 63;
    const int rg = tid >> 6;
    float acc[8][4] = {};
    for (int k0 = 0; k0 < K; k0 += BK){
        for (int idx = tid; idx < BK*DH; idx += 256)
            ldsW[idx] = W[(size_t)k0*DH + idx];
        for (int idx = tid; idx < BM*BK; idx += 256){
            int r = idx / BK, k = idx % BK;
            int row = row0 + r;
            ldsX[idx] = (row < M) ? A[(size_t)row*K + k0 + k] : 0.f;
        }
        __syncthreads();
        for (int k = 0; k < BK; ++k){
            const float4 wv = *(const float4*)(&ldsW[k*DH + jc*4]);
            #pragma unroll
            for (int r = 0; r < 8; ++r){
                float xv = ldsX[(rg*8 + r)*BK + k];
                acc[r][0] += xv*wv.x; acc[r][1] += xv*wv.y;
                acc[r][2] += xv*wv.z; acc[r][3] += xv*wv.w;
            }
        }
        __syncthreads();
    }
    const float4 bv = *(const float4*)(&bias[jc*4]);
    #pragma unroll
    for (int r = 0; r < 8; ++r){
        int row = row0 + rg*8 + r;
        if (row < M){
            ushort4 o;
            o.x = f2bf(acc[r][0] + bv.x);
            o.y = f2bf(acc[r][1] + bv.y);
            o.z = f2bf(acc[r][2] + bv.z);
            o.w = f2bf(acc[r][3] + bv.w);
            *(ushort4*)(&out[(size_t)row*DH + jc*4]) = o;
        }
    }
}

// ---------------- w2 transpose + bf16 convert: w2t[n][k] ----------------
__global__ void k_w2t(const float* __restrict__ w2, unsigned short* __restrict__ w2t){
    int idx = blockIdx.x*256 + threadIdx.x;
    int n = idx >> 8, k = idx & 255;
    w2t[idx] = f2bf(w2[k*DH + n]);
}

// ---------------- GEMM2: bf16 MFMA 16x16x32; A=h (m,k), B=w2t (n,k) ----------------
__global__ __launch_bounds__(256) void k_gemm2(const unsigned short* __restrict__ h,
                                               const unsigned short* __restrict__ w2t,
                                               const float* __restrict__ bias,
                                               unsigned short* __restrict__ out, int M){
    const int wave = threadIdx.x >> 6;
    const int lane = threadIdx.x & 63;
    const int row0 = (blockIdx.x*4 + wave) * 16;
    if (row0 >= M) return;
    const int r = lane & 15;
    const int g = lane >> 4;
    f32x4 acc[16];
    #pragma unroll
    for (int n = 0; n < 16; ++n) acc[n] = (f32x4){0.f,0.f,0.f,0.f};
    #pragma unroll
    for (int kk = 0; kk < DH/32; ++kk){
        const int k0 = kk*32;
        bf16x8 a = *(const bf16x8*)(h + (size_t)(row0 + r)*DH + k0 + g*8);
        #pragma unroll
        for (int n = 0; n < 16; ++n){
            bf16x8 bfr = *(const bf16x8*)(w2t + (size_t)(n*16 + r)*DH + k0 + g*8);
            acc[n] = __builtin_amdgcn_mfma_f32_16x16x32_bf16(a, bfr, acc[n], 0, 0, 0);
        }
    }
    #pragma unroll
    for (int n = 0; n < 16; ++n){
        float bv = bias[n*16 + r];
        #pragma unroll
        for (int j = 0; j < 4; ++j){
            int row = row0 + g*4 + j;   // C: col=lane&15, row=(lane>>4)*4+reg
            out[(size_t)row*DH + n*16 + r] = f2bf(acc[n][j] + bv);
        }
    }
}

// ---------------- SPMM layer1 (gather by dst-CSR, fused LeakyReLU) ----------------
__global__ __launch_bounds__(256) void k_spmm1(const unsigned short* __restrict__ feat,
                                               const int* __restrict__ row_start,
                                               const unsigned short* __restrict__ colS,
                                               const float* __restrict__ att,
                                               unsigned short* __restrict__ out){
    int row = blockIdx.x*4 + (threadIdx.x >> 6);
    int lane = threadIdx.x & 63;
    if (row >= NN) return;
    float a0=0.f, a1=0.f, a2=0.f, a3=0.f;
    #pragma unroll
    for (int i = 0; i < NRELS; ++i){
        const int s0 = row_start[i*(NN+1) + row];
        const int s1 = row_start[i*(NN+1) + row + 1];
        if (s1 > s0){
            float t0=0.f, t1=0.f, t2=0.f, t3=0.f;
            for (int slot = s0; slot < s1; ++slot){
                int c = (int)colS[slot];
                ushort4 u = *(const ushort4*)(feat + (size_t)c*DH + lane*4);
                t0 += bf2f(u.x); t1 += bf2f(u.y); t2 += bf2f(u.z); t3 += bf2f(u.w);
            }
            float v = att[i] / (float)(s1 - s0);   // = att[i] * (1/indeg)
            a0 += v*t0; a1 += v*t1; a2 += v*t2; a3 += v*t3;
        }
    }
    a0 = a0 > 0.f ? a0 : 0.2f*a0;
    a1 = a1 > 0.f ? a1 : 0.2f*a1;
    a2 = a2 > 0.f ? a2 : 0.2f*a2;
    a3 = a3 > 0.f ? a3 : 0.2f*a3;
    ushort4 o; o.x = f2bf(a0); o.y = f2bf(a1); o.z = f2bf(a2); o.w = f2bf(a3);
    *(ushort4*)(&out[(size_t)row*DH + lane*4]) = o;
}

// ---------------- SPMM layer2 (gather by src-CSR, fused L2 normalize) ----------------
__global__ __launch_bounds__(256) void k_spmm2(const unsigned short* __restrict__ feat,
                                               const int* __restrict__ row_start,
                                               const unsigned short* __restrict__ colS,
                                               const float* __restrict__ att,
                                               float* __restrict__ out){
    int row = blockIdx.x*4 + (threadIdx.x >> 6);
    int lane = threadIdx.x & 63;
    if (row >= NN) return;
    float a0=0.f, a1=0.f, a2=0.f, a3=0.f;
    #pragma unroll
    for (int i = 0; i < NRELS; ++i){
        const int a = NRELS + i;
        const int s0 = row_start[a*(NN+1) + row];
        const int s1 = row_start[a*(NN+1) + row + 1];
        if (s1 > s0){
            float t0=0.f, t1=0.f, t2=0.f, t3=0.f;
            for (int slot = s0; slot < s1; ++slot){
                int c = (int)colS[slot];
                ushort4 u = *(const ushort4*)(feat + (size_t)c*DH + lane*4);
                t0 += bf2f(u.x); t1 += bf2f(u.y); t2 += bf2f(u.z); t3 += bf2f(u.w);
            }
            float v = att[a] / (float)(s1 - s0);   // = att2[i] * (1/outdeg)
            a0 += v*t0; a1 += v*t1; a2 += v*t2; a3 += v*t3;
        }
    }
    float ss = a0*a0 + a1*a1 + a2*a2 + a3*a3;
    #pragma unroll
    for (int off = 32; off > 0; off >>= 1) ss += __shfl_xor(ss, off);
    float scale = 1.0f / fmaxf(sqrtf(ss), 1e-12f);
    float4 o; o.x = a0*scale; o.y = a1*scale; o.z = a2*scale; o.w = a3*scale;
    *(float4*)(&out[(size_t)row*DH + lane*4]) = o;
}

extern "C" void kernel_launch(void* const* d_in, const int* in_sizes, int n_in,
                              void* d_out, int out_size, void* d_ws, size_t ws_size,
                              hipStream_t stream){
    const float* x      = (const float*)d_in[0];
    const float* w1     = (const float*)d_in[1];
    const float* b1     = (const float*)d_in[2];
    const float* w2     = (const float*)d_in[3];
    const float* b2     = (const float*)d_in[4];
    const float* a_att  = (const float*)d_in[5];
    const float* r_att  = (const float*)d_in[6];
    const int*   src    = (const int*)d_in[7];
    const int*   dst    = (const int*)d_in[8];
    float* out = (float*)d_out;

    char* ws = (char*)d_ws;
    size_t off = 0;
    auto take = [&](size_t bytes)->char*{
        char* p = ws + off;
        off = (off + bytes + 255) & ~(size_t)255;
        return p;
    };
    float*          att         = (float*)take(6*sizeof(float));
    unsigned short* sbuf        = (unsigned short*)take((size_t)NN*DH*2); // s, later s2
    unsigned short* hbuf        = (unsigned short*)take((size_t)NN*DH*2); // h
    unsigned short* w2t         = (unsigned short*)take((size_t)DH*DH*2);
    int*            bcount      = (int*)take((size_t)NBT*PAD*4);
    int*            bucket_base = (int*)take((size_t)(NBT+1)*4);
    int*            row_start   = (int*)take((size_t)6*(NN+1)*4);
    unsigned int*   bucketbuf   = (unsigned int*)take((size_t)6*NE*4);
    unsigned short* colS        = (unsigned short*)take((size_t)6*NE*2);
    (void)ws_size; (void)in_sizes; (void)n_in; (void)out_size;

    hipMemsetAsync(bcount, 0, (size_t)NBT*PAD*4, stream);

    k_att<<<1, 64, 0, stream>>>(a_att, r_att, att);
    k_w2t<<<(DH*DH + 255)/256, 256, 0, stream>>>(w2, w2t);

    dim3 egrid((NE + 255)/256, NRELS);
    k_bhist<<<egrid, 256, 0, stream>>>(src, dst, bcount);
    k_bscan<<<1, 256, 0, stream>>>(bcount, bucket_base);
    k_bscatter<<<egrid, 256, 0, stream>>>(src, dst, bcount, bucketbuf);
    k_bfinal<<<NBT, 256, 0, stream>>>(bucketbuf, bucket_base, row_start, colS);

    // layer 1: s = x@w1+b1 ; h = leaky(sum_i att[i]*spmm_i(s))
    k_gemm<DIN, 50><<<(NN + 31)/32, 256, 0, stream>>>(x, w1, b1, sbuf, NN);
    k_spmm1<<<(NN + 3)/4, 256, 0, stream>>>(sbuf, row_start, colS, att, hbuf);

    // layer 2: s2 = h@w2+b2 (MFMA) ; out = normalize(sum att2*spmm(s2))
    k_gemm2<<<(NN/16 + 3)/4, 256, 0, stream>>>(hbuf, w2t, b2, sbuf, NN);
    k_spmm2<<<(NN + 3)/4, 256, 0, stream>>>(sbuf, row_start, colS, att, out);
}

// Round 4
// 967.563 us; speedup vs baseline: 1.7646x; 1.7646x over previous
//
#include <hip/hip_runtime.h>
#include <stdint.h>

#define NN 50000      // nodes
#define NRELS 3       // relations
#define NE 800000     // edges per relation
#define DIN 300
#define DH 256
#define NBUK 196      // ceil(NN/256) row-buckets per CSR set
#define NBT (6*NBUK)  // 1176 buckets total
#define PAD 16        // ints per bucket cursor (one 64B line)
#define CAP 5120      // slots per bucket (mean 4096, sigma 64 -> 16 sigma headroom)
#define CHUNK 4096    // edges per scatter block
#define NLB 392       // local buckets per scatter block (2 sets x 196)

typedef __attribute__((ext_vector_type(8))) short bf16x8;
typedef __attribute__((ext_vector_type(4))) float f32x4;

__device__ __forceinline__ float bf2f(unsigned short u){
    union { unsigned int i; float f; } v; v.i = ((unsigned int)u) << 16; return v.f;
}
__device__ __forceinline__ unsigned short f2bf(float f){
    union { float f; unsigned int i; } v; v.f = f;
    return (unsigned short)((v.i + 0x7FFFu + ((v.i >> 16) & 1u)) >> 16);
}

// ---------------- attention softmax (6 scalars) ----------------
__global__ void k_att(const float* __restrict__ a_att, const float* __restrict__ r_att,
                      float* __restrict__ att){
    if (threadIdx.x == 0){
        float m = fmaxf(a_att[0], fmaxf(a_att[1], a_att[2]));
        float e0 = expf(a_att[0]-m), e1 = expf(a_att[1]-m), e2 = expf(a_att[2]-m);
        float s = e0+e1+e2;
        att[0]=e0/s; att[1]=e1/s; att[2]=e2/s;
        m = fmaxf(r_att[0], fmaxf(r_att[1], r_att[2]));
        e0 = expf(r_att[0]-m); e1 = expf(r_att[1]-m); e2 = expf(r_att[2]-m);
        s = e0+e1+e2;
        att[3]=e0/s; att[4]=e1/s; att[5]=e2/s;
    }
}

// ---------------- cursor init: bucket b starts at b*CAP ----------------
__global__ void k_binit(int* __restrict__ bcur){
    int b = blockIdx.x*256 + threadIdx.x;
    if (b < NBT) bcur[b*PAD] = b*CAP;
}

// ---------------- block-aggregated scatter ----------------
__global__ __launch_bounds__(256) void k_bscatter_agg(const int* __restrict__ src,
                                                      const int* __restrict__ dst,
                                                      int* __restrict__ bcur,
                                                      unsigned int* __restrict__ bucketbuf){
    __shared__ unsigned int ledge[2*CHUNK];     // 32 KB
    __shared__ unsigned short lbid[2*CHUNK];    // 16 KB
    __shared__ int lhist[448];                  // padded to 64*7
    __shared__ int lstart[NLB];
    __shared__ int gbase[NLB];
    __shared__ int glim[NLB];
    const int rel = blockIdx.y;
    const int e0 = blockIdx.x*CHUNK;
    const int tid = threadIdx.x;
    for (int i = tid; i < 448; i += 256) lhist[i] = 0;
    __syncthreads();
    int sv[16], dv[16];
    #pragma unroll
    for (int j = 0; j < 16; ++j){
        int e = e0 + j*256 + tid;
        if (e < NE){
            sv[j] = src[(size_t)rel*NE + e];
            dv[j] = dst[(size_t)rel*NE + e];
            atomicAdd(&lhist[dv[j] >> 8], 1);          // layer1 bucket (row=dst)
            atomicAdd(&lhist[196 + (sv[j] >> 8)], 1);  // layer2 bucket (row=src)
        } else sv[j] = -1;
    }
    __syncthreads();
    // exclusive scan of 448 slots: wave 0, 7 slots per lane
    if (tid < 64){
        int base = tid*7, s = 0, tmp[7];
        #pragma unroll
        for (int j = 0; j < 7; ++j){ tmp[j] = s; s += lhist[base+j]; }
        int run = s;
        #pragma unroll
        for (int off_ = 1; off_ < 64; off_ <<= 1){
            int t = __shfl_up(run, off_);
            if (tid >= off_) run += t;
        }
        int excl = run - s;
        #pragma unroll
        for (int j = 0; j < 7; ++j) lhist[base+j] = tmp[j] + excl;
    }
    __syncthreads();
    for (int i = tid; i < NLB; i += 256) lstart[i] = lhist[i];
    __syncthreads();
    // place entries bucket-sorted into LDS (lhist doubles as cursor)
    #pragma unroll
    for (int j = 0; j < 16; ++j){
        if (sv[j] >= 0){
            int lb = dv[j] >> 8;
            int pos = atomicAdd(&lhist[lb], 1);
            ledge[pos] = ((unsigned)(dv[j] & 255) << 16) | (unsigned)sv[j];
            lbid[pos] = (unsigned short)lb;
            lb = 196 + (sv[j] >> 8);
            pos = atomicAdd(&lhist[lb], 1);
            ledge[pos] = ((unsigned)(sv[j] & 255) << 16) | (unsigned)dv[j];
            lbid[pos] = (unsigned short)lb;
        }
    }
    __syncthreads();
    // one aggregated global reservation per non-empty local bucket
    for (int lb = tid; lb < NLB; lb += 256){
        int cnt = lhist[lb] - lstart[lb];
        if (cnt > 0){
            int gb = (lb < 196) ? (rel*NBUK + lb) : ((NRELS+rel)*NBUK + lb - 196);
            int base = atomicAdd(&bcur[gb*PAD], cnt);
            gbase[lb] = base;
            glim[lb]  = min(base + cnt, gb*CAP + CAP);  // overflow clamp
        }
    }
    __syncthreads();
    // coalesced run writes
    const int total = min(NE - e0, CHUNK)*2;
    for (int i = tid; i < total; i += 256){
        int lb = lbid[i];
        int dest = gbase[lb] + (i - lstart[lb]);
        if (dest < glim[lb]) bucketbuf[dest] = ledge[i];
    }
}

// ---------------- per-bucket finalize: row_start/row_end + sorted colS ----------------
__global__ __launch_bounds__(256) void k_bfinal(const unsigned int* __restrict__ bucketbuf,
                                                const int* __restrict__ bcur,
                                                int* __restrict__ row_start,
                                                int* __restrict__ row_end,
                                                unsigned short* __restrict__ colS){
    __shared__ int lhist[256];
    __shared__ int lcur[256];
    __shared__ unsigned int ledge[CAP];
    int b = blockIdx.x;
    int a = b / NBUK, bu = b % NBUK;
    int row0 = bu << 8;
    int base = b*CAP;
    int cnt = min(bcur[b*PAD] - base, CAP);
    int tid = threadIdx.x;
    lhist[tid] = 0;
    __syncthreads();
    for (int i = tid; i < cnt; i += 256){
        unsigned int p = bucketbuf[base + i];
        ledge[i] = p;
        atomicAdd(&lhist[p >> 16], 1);
    }
    __syncthreads();
    int v = lhist[tid];
    for (int off_ = 1; off_ < 256; off_ <<= 1){
        int t = (tid >= off_) ? lhist[tid - off_] : 0;
        __syncthreads();
        lhist[tid] += t;
        __syncthreads();
    }
    int excl = lhist[tid] - v;
    lcur[tid] = excl;
    int rows = NN - row0; if (rows > 256) rows = 256;
    if (tid < rows){
        row_start[a*NN + row0 + tid] = base + excl;
        row_end[a*NN + row0 + tid]   = base + excl + v;
    }
    __syncthreads();
    for (int i = tid; i < cnt; i += 256){
        unsigned int p = ledge[i];
        int pos = atomicAdd(&lcur[p >> 16], 1);
        colS[base + pos] = (unsigned short)(p & 0xFFFFu);
    }
}

// ---------------- GEMM1: f32 VALU, out[m][n] = A@W + b, bf16 out ----------------
template<int K, int BK>
__global__ __launch_bounds__(256) void k_gemm(const float* __restrict__ A,
                                              const float* __restrict__ W,
                                              const float* __restrict__ bias,
                                              unsigned short* __restrict__ out, int M){
    constexpr int BM = 32;
    __shared__ float ldsW[BK*DH];
    __shared__ float ldsX[BM*BK];
    const int tid = threadIdx.x;
    const int row0 = blockIdx.x * BM;
    const int jc = tid & 63;
    const int rg = tid >> 6;
    float acc[8][4] = {};
    for (int k0 = 0; k0 < K; k0 += BK){
        for (int idx = tid; idx < BK*DH; idx += 256)
            ldsW[idx] = W[(size_t)k0*DH + idx];
        for (int idx = tid; idx < BM*BK; idx += 256){
            int r = idx / BK, k = idx % BK;
            int row = row0 + r;
            ldsX[idx] = (row < M) ? A[(size_t)row*K + k0 + k] : 0.f;
        }
        __syncthreads();
        for (int k = 0; k < BK; ++k){
            const float4 wv = *(const float4*)(&ldsW[k*DH + jc*4]);
            #pragma unroll
            for (int r = 0; r < 8; ++r){
                float xv = ldsX[(rg*8 + r)*BK + k];
                acc[r][0] += xv*wv.x; acc[r][1] += xv*wv.y;
                acc[r][2] += xv*wv.z; acc[r][3] += xv*wv.w;
            }
        }
        __syncthreads();
    }
    const float4 bv = *(const float4*)(&bias[jc*4]);
    #pragma unroll
    for (int r = 0; r < 8; ++r){
        int row = row0 + rg*8 + r;
        if (row < M){
            ushort4 o;
            o.x = f2bf(acc[r][0] + bv.x);
            o.y = f2bf(acc[r][1] + bv.y);
            o.z = f2bf(acc[r][2] + bv.z);
            o.w = f2bf(acc[r][3] + bv.w);
            *(ushort4*)(&out[(size_t)row*DH + jc*4]) = o;
        }
    }
}

// ---------------- w2 transpose + bf16 convert: w2t[n][k] ----------------
__global__ void k_w2t(const float* __restrict__ w2, unsigned short* __restrict__ w2t){
    int idx = blockIdx.x*256 + threadIdx.x;
    int n = idx >> 8, k = idx & 255;
    w2t[idx] = f2bf(w2[k*DH + n]);
}

// ---------------- GEMM2: bf16 MFMA 16x16x32; A=h (m,k), B=w2t (n,k) ----------------
__global__ __launch_bounds__(256) void k_gemm2(const unsigned short* __restrict__ h,
                                               const unsigned short* __restrict__ w2t,
                                               const float* __restrict__ bias,
                                               unsigned short* __restrict__ out, int M){
    const int wave = threadIdx.x >> 6;
    const int lane = threadIdx.x & 63;
    const int row0 = (blockIdx.x*4 + wave) * 16;
    if (row0 >= M) return;
    const int r = lane & 15;
    const int g = lane >> 4;
    f32x4 acc[16];
    #pragma unroll
    for (int n = 0; n < 16; ++n) acc[n] = (f32x4){0.f,0.f,0.f,0.f};
    #pragma unroll
    for (int kk = 0; kk < DH/32; ++kk){
        const int k0 = kk*32;
        bf16x8 a = *(const bf16x8*)(h + (size_t)(row0 + r)*DH + k0 + g*8);
        #pragma unroll
        for (int n = 0; n < 16; ++n){
            bf16x8 bfr = *(const bf16x8*)(w2t + (size_t)(n*16 + r)*DH + k0 + g*8);
            acc[n] = __builtin_amdgcn_mfma_f32_16x16x32_bf16(a, bfr, acc[n], 0, 0, 0);
        }
    }
    #pragma unroll
    for (int n = 0; n < 16; ++n){
        float bv = bias[n*16 + r];
        #pragma unroll
        for (int j = 0; j < 4; ++j){
            int row = row0 + g*4 + j;   // C: col=lane&15, row=(lane>>4)*4+reg
            out[(size_t)row*DH + n*16 + r] = f2bf(acc[n][j] + bv);
        }
    }
}

// ---------------- SPMM layer1 (gather by dst-CSR, fused LeakyReLU) ----------------
__global__ __launch_bounds__(256) void k_spmm1(const unsigned short* __restrict__ feat,
                                               const int* __restrict__ row_start,
                                               const int* __restrict__ row_end,
                                               const unsigned short* __restrict__ colS,
                                               const float* __restrict__ att,
                                               unsigned short* __restrict__ out){
    int row = blockIdx.x*4 + (threadIdx.x >> 6);
    int lane = threadIdx.x & 63;
    if (row >= NN) return;
    float a0=0.f, a1=0.f, a2=0.f, a3=0.f;
    #pragma unroll
    for (int i = 0; i < NRELS; ++i){
        const int s0 = row_start[i*NN + row];
        const int s1 = row_end[i*NN + row];
        if (s1 > s0){
            float t0=0.f, t1=0.f, t2=0.f, t3=0.f;
            for (int slot = s0; slot < s1; ++slot){
                int c = (int)colS[slot];
                ushort4 u = *(const ushort4*)(feat + (size_t)c*DH + lane*4);
                t0 += bf2f(u.x); t1 += bf2f(u.y); t2 += bf2f(u.z); t3 += bf2f(u.w);
            }
            float v = att[i] / (float)(s1 - s0);   // = att[i] * (1/indeg)
            a0 += v*t0; a1 += v*t1; a2 += v*t2; a3 += v*t3;
        }
    }
    a0 = a0 > 0.f ? a0 : 0.2f*a0;
    a1 = a1 > 0.f ? a1 : 0.2f*a1;
    a2 = a2 > 0.f ? a2 : 0.2f*a2;
    a3 = a3 > 0.f ? a3 : 0.2f*a3;
    ushort4 o; o.x = f2bf(a0); o.y = f2bf(a1); o.z = f2bf(a2); o.w = f2bf(a3);
    *(ushort4*)(&out[(size_t)row*DH + lane*4]) = o;
}

// ---------------- SPMM layer2 (gather by src-CSR, fused L2 normalize) ----------------
__global__ __launch_bounds__(256) void k_spmm2(const unsigned short* __restrict__ feat,
                                               const int* __restrict__ row_start,
                                               const int* __restrict__ row_end,
                                               const unsigned short* __restrict__ colS,
                                               const float* __restrict__ att,
                                               float* __restrict__ out){
    int row = blockIdx.x*4 + (threadIdx.x >> 6);
    int lane = threadIdx.x & 63;
    if (row >= NN) return;
    float a0=0.f, a1=0.f, a2=0.f, a3=0.f;
    #pragma unroll
    for (int i = 0; i < NRELS; ++i){
        const int a = NRELS + i;
        const int s0 = row_start[a*NN + row];
        const int s1 = row_end[a*NN + row];
        if (s1 > s0){
            float t0=0.f, t1=0.f, t2=0.f, t3=0.f;
            for (int slot = s0; slot < s1; ++slot){
                int c = (int)colS[slot];
                ushort4 u = *(const ushort4*)(feat + (size_t)c*DH + lane*4);
                t0 += bf2f(u.x); t1 += bf2f(u.y); t2 += bf2f(u.z); t3 += bf2f(u.w);
            }
            float v = att[a] / (float)(s1 - s0);   // = att2[i] * (1/outdeg)
            a0 += v*t0; a1 += v*t1; a2 += v*t2; a3 += v*t3;
        }
    }
    float ss = a0*a0 + a1*a1 + a2*a2 + a3*a3;
    #pragma unroll
    for (int off = 32; off > 0; off >>= 1) ss += __shfl_xor(ss, off);
    float scale = 1.0f / fmaxf(sqrtf(ss), 1e-12f);
    float4 o; o.x = a0*scale; o.y = a1*scale; o.z = a2*scale; o.w = a3*scale;
    *(float4*)(&out[(size_t)row*DH + lane*4]) = o;
}

extern "C" void kernel_launch(void* const* d_in, const int* in_sizes, int n_in,
                              void* d_out, int out_size, void* d_ws, size_t ws_size,
                              hipStream_t stream){
    const float* x      = (const float*)d_in[0];
    const float* w1     = (const float*)d_in[1];
    const float* b1     = (const float*)d_in[2];
    const float* w2     = (const float*)d_in[3];
    const float* b2     = (const float*)d_in[4];
    const float* a_att  = (const float*)d_in[5];
    const float* r_att  = (const float*)d_in[6];
    const int*   src    = (const int*)d_in[7];
    const int*   dst    = (const int*)d_in[8];
    float* out = (float*)d_out;

    char* ws = (char*)d_ws;
    size_t off = 0;
    auto take = [&](size_t bytes)->char*{
        char* p = ws + off;
        off = (off + bytes + 255) & ~(size_t)255;
        return p;
    };
    float*          att         = (float*)take(6*sizeof(float));
    unsigned short* sbuf        = (unsigned short*)take((size_t)NN*DH*2); // s, later s2
    unsigned short* hbuf        = (unsigned short*)take((size_t)NN*DH*2); // h
    unsigned short* w2t         = (unsigned short*)take((size_t)DH*DH*2);
    int*            bcur        = (int*)take((size_t)NBT*PAD*4);
    int*            row_start   = (int*)take((size_t)6*NN*4);
    int*            row_end     = (int*)take((size_t)6*NN*4);
    unsigned int*   bucketbuf   = (unsigned int*)take((size_t)NBT*CAP*4);
    unsigned short* colS        = (unsigned short*)take((size_t)NBT*CAP*2);
    (void)ws_size; (void)in_sizes; (void)n_in; (void)out_size;

    k_att<<<1, 64, 0, stream>>>(a_att, r_att, att);
    k_w2t<<<(DH*DH + 255)/256, 256, 0, stream>>>(w2, w2t);
    k_binit<<<(NBT + 255)/256, 256, 0, stream>>>(bcur);

    dim3 sgrid((NE + CHUNK - 1)/CHUNK, NRELS);
    k_bscatter_agg<<<sgrid, 256, 0, stream>>>(src, dst, bcur, bucketbuf);
    k_bfinal<<<NBT, 256, 0, stream>>>(bucketbuf, bcur, row_start, row_end, colS);

    // layer 1: s = x@w1+b1 ; h = leaky(sum_i att[i]*spmm_i(s))
    k_gemm<DIN, 50><<<(NN + 31)/32, 256, 0, stream>>>(x, w1, b1, sbuf, NN);
    k_spmm1<<<(NN + 3)/4, 256, 0, stream>>>(sbuf, row_start, row_end, colS, att, hbuf);

    // layer 2: s2 = h@w2+b2 (MFMA) ; out = normalize(sum att2*spmm(s2))
    k_gemm2<<<(NN/16 + 3)/4, 256, 0, stream>>>(hbuf, w2t, b2, sbuf, NN);
    k_spmm2<<<(NN + 3)/4, 256, 0, stream>>>(sbuf, row_start, row_end, colS, att, out);
}

// Round 5
// 695.427 us; speedup vs baseline: 2.4552x; 1.3913x over previous
//
#include <hip/hip_runtime.h>
#include <stdint.h>

#define NN 50000      // nodes
#define NRELS 3       // relations
#define NE 800000     // edges per relation
#define DIN 300
#define KP 320        // DIN padded to multiple of 32
#define DH 256
#define NBUK 196      // ceil(NN/256) row-buckets per CSR set
#define NBT (6*NBUK)  // 1176 buckets total
#define PAD 16        // ints per bucket cursor (one 64B line)
#define CAP 5120      // slots per bucket (mean 4096, sigma 64 -> 16 sigma headroom)
#define CHUNK 4096    // edges per scatter block
#define NLB 392       // local buckets per scatter block (2 sets x 196)

typedef __attribute__((ext_vector_type(8))) short bf16x8;
typedef __attribute__((ext_vector_type(4))) float f32x4;

__device__ __forceinline__ float bf2f(unsigned short u){
    union { unsigned int i; float f; } v; v.i = ((unsigned int)u) << 16; return v.f;
}
__device__ __forceinline__ unsigned short f2bf(float f){
    union { float f; unsigned int i; } v; v.f = f;
    return (unsigned short)((v.i + 0x7FFFu + ((v.i >> 16) & 1u)) >> 16);
}

// ---------------- attention softmax (6 scalars) ----------------
__global__ void k_att(const float* __restrict__ a_att, const float* __restrict__ r_att,
                      float* __restrict__ att){
    if (threadIdx.x == 0){
        float m = fmaxf(a_att[0], fmaxf(a_att[1], a_att[2]));
        float e0 = expf(a_att[0]-m), e1 = expf(a_att[1]-m), e2 = expf(a_att[2]-m);
        float s = e0+e1+e2;
        att[0]=e0/s; att[1]=e1/s; att[2]=e2/s;
        m = fmaxf(r_att[0], fmaxf(r_att[1], r_att[2]));
        e0 = expf(r_att[0]-m); e1 = expf(r_att[1]-m); e2 = expf(r_att[2]-m);
        s = e0+e1+e2;
        att[3]=e0/s; att[4]=e1/s; att[5]=e2/s;
    }
}

// ---------------- cursor init: bucket b starts at b*CAP ----------------
__global__ void k_binit(int* __restrict__ bcur){
    int b = blockIdx.x*256 + threadIdx.x;
    if (b < NBT) bcur[b*PAD] = b*CAP;
}

// ---------------- block-aggregated scatter ----------------
__global__ __launch_bounds__(256) void k_bscatter_agg(const int* __restrict__ src,
                                                      const int* __restrict__ dst,
                                                      int* __restrict__ bcur,
                                                      unsigned int* __restrict__ bucketbuf){
    __shared__ unsigned int ledge[2*CHUNK];     // 32 KB
    __shared__ unsigned short lbid[2*CHUNK];    // 16 KB
    __shared__ int lhist[448];                  // padded to 64*7
    __shared__ int lstart[NLB];
    __shared__ int gbase[NLB];
    __shared__ int glim[NLB];
    const int rel = blockIdx.y;
    const int e0 = blockIdx.x*CHUNK;
    const int tid = threadIdx.x;
    for (int i = tid; i < 448; i += 256) lhist[i] = 0;
    __syncthreads();
    int sv[16], dv[16];
    #pragma unroll
    for (int j = 0; j < 16; ++j){
        int e = e0 + j*256 + tid;
        if (e < NE){
            sv[j] = src[(size_t)rel*NE + e];
            dv[j] = dst[(size_t)rel*NE + e];
            atomicAdd(&lhist[dv[j] >> 8], 1);          // layer1 bucket (row=dst)
            atomicAdd(&lhist[196 + (sv[j] >> 8)], 1);  // layer2 bucket (row=src)
        } else sv[j] = -1;
    }
    __syncthreads();
    // exclusive scan of 448 slots: wave 0, 7 slots per lane
    if (tid < 64){
        int base = tid*7, s = 0, tmp[7];
        #pragma unroll
        for (int j = 0; j < 7; ++j){ tmp[j] = s; s += lhist[base+j]; }
        int run = s;
        #pragma unroll
        for (int off_ = 1; off_ < 64; off_ <<= 1){
            int t = __shfl_up(run, off_);
            if (tid >= off_) run += t;
        }
        int excl = run - s;
        #pragma unroll
        for (int j = 0; j < 7; ++j) lhist[base+j] = tmp[j] + excl;
    }
    __syncthreads();
    for (int i = tid; i < NLB; i += 256) lstart[i] = lhist[i];
    __syncthreads();
    // place entries bucket-sorted into LDS (lhist doubles as cursor)
    #pragma unroll
    for (int j = 0; j < 16; ++j){
        if (sv[j] >= 0){
            int lb = dv[j] >> 8;
            int pos = atomicAdd(&lhist[lb], 1);
            ledge[pos] = ((unsigned)(dv[j] & 255) << 16) | (unsigned)sv[j];
            lbid[pos] = (unsigned short)lb;
            lb = 196 + (sv[j] >> 8);
            pos = atomicAdd(&lhist[lb], 1);
            ledge[pos] = ((unsigned)(sv[j] & 255) << 16) | (unsigned)dv[j];
            lbid[pos] = (unsigned short)lb;
        }
    }
    __syncthreads();
    // one aggregated global reservation per non-empty local bucket
    for (int lb = tid; lb < NLB; lb += 256){
        int cnt = lhist[lb] - lstart[lb];
        if (cnt > 0){
            int gb = (lb < 196) ? (rel*NBUK + lb) : ((NRELS+rel)*NBUK + lb - 196);
            int base = atomicAdd(&bcur[gb*PAD], cnt);
            gbase[lb] = base;
            glim[lb]  = min(base + cnt, gb*CAP + CAP);  // overflow clamp
        }
    }
    __syncthreads();
    // coalesced run writes
    const int total = min(NE - e0, CHUNK)*2;
    for (int i = tid; i < total; i += 256){
        int lb = lbid[i];
        int dest = gbase[lb] + (i - lstart[lb]);
        if (dest < glim[lb]) bucketbuf[dest] = ledge[i];
    }
}

// ---------------- per-bucket finalize: row_start/row_end + sorted colS ----------------
__global__ __launch_bounds__(256) void k_bfinal(const unsigned int* __restrict__ bucketbuf,
                                                const int* __restrict__ bcur,
                                                int* __restrict__ row_start,
                                                int* __restrict__ row_end,
                                                unsigned short* __restrict__ colS){
    __shared__ int lhist[256];
    __shared__ int lcur[256];
    __shared__ unsigned int ledge[CAP];
    int b = blockIdx.x;
    int a = b / NBUK, bu = b % NBUK;
    int row0 = bu << 8;
    int base = b*CAP;
    int cnt = min(bcur[b*PAD] - base, CAP);
    int tid = threadIdx.x;
    lhist[tid] = 0;
    __syncthreads();
    for (int i = tid; i < cnt; i += 256){
        unsigned int p = bucketbuf[base + i];
        ledge[i] = p;
        atomicAdd(&lhist[p >> 16], 1);
    }
    __syncthreads();
    int v = lhist[tid];
    for (int off_ = 1; off_ < 256; off_ <<= 1){
        int t = (tid >= off_) ? lhist[tid - off_] : 0;
        __syncthreads();
        lhist[tid] += t;
        __syncthreads();
    }
    int excl = lhist[tid] - v;
    lcur[tid] = excl;
    int rows = NN - row0; if (rows > 256) rows = 256;
    if (tid < rows){
        row_start[a*NN + row0 + tid] = base + excl;
        row_end[a*NN + row0 + tid]   = base + excl + v;
    }
    __syncthreads();
    for (int i = tid; i < cnt; i += 256){
        unsigned int p = ledge[i];
        int pos = atomicAdd(&lcur[p >> 16], 1);
        colS[base + pos] = (unsigned short)(p & 0xFFFFu);
    }
}

// ---------------- w1 transpose+pad: w1t[n][k] bf16, k<KP (0 beyond DIN) ----------------
__global__ void k_w1t(const float* __restrict__ w1, unsigned short* __restrict__ w1t){
    int idx = blockIdx.x*256 + threadIdx.x;   // over [256][KP]
    int n = idx / KP, k = idx % KP;
    w1t[idx] = (k < DIN) ? f2bf(w1[(size_t)k*DH + n]) : 0;
}

// ---------------- w2 transpose + bf16 convert: w2t[n][k] ----------------
__global__ void k_w2t(const float* __restrict__ w2, unsigned short* __restrict__ w2t){
    int idx = blockIdx.x*256 + threadIdx.x;
    int n = idx >> 8, k = idx & 255;
    w2t[idx] = f2bf(w2[k*DH + n]);
}

// ---------------- GEMM1: MFMA bf16; A=x (f32, converted inline), B=w1t ----------------
__global__ __launch_bounds__(256) void k_gemm1(const float* __restrict__ x,
                                               const unsigned short* __restrict__ w1t,
                                               const float* __restrict__ bias,
                                               unsigned short* __restrict__ out, int M){
    const int wave = threadIdx.x >> 6;
    const int lane = threadIdx.x & 63;
    const int row0 = (blockIdx.x*4 + wave) * 16;
    if (row0 >= M) return;
    const int r = lane & 15;
    const int g = lane >> 4;
    const float* xrow = x + (size_t)(row0 + r)*DIN;
    f32x4 acc[16];
    #pragma unroll
    for (int n = 0; n < 16; ++n) acc[n] = (f32x4){0.f,0.f,0.f,0.f};
    #pragma unroll
    for (int kk = 0; kk < KP/32; ++kk){
        const int k0 = kk*32 + g*8;
        bf16x8 a;
        if (kk < 9){                       // k0+7 <= 287+8 < DIN: full vector loads
            float4 xa = *(const float4*)(xrow + k0);
            float4 xb = *(const float4*)(xrow + k0 + 4);
            a[0]=(short)f2bf(xa.x); a[1]=(short)f2bf(xa.y);
            a[2]=(short)f2bf(xa.z); a[3]=(short)f2bf(xa.w);
            a[4]=(short)f2bf(xb.x); a[5]=(short)f2bf(xb.y);
            a[6]=(short)f2bf(xb.z); a[7]=(short)f2bf(xb.w);
        } else {                           // tail: guard OOB (B is 0 beyond DIN anyway)
            #pragma unroll
            for (int j = 0; j < 8; ++j){
                int k = k0 + j;
                a[j] = (short)((k < DIN) ? f2bf(xrow[k]) : 0);
            }
        }
        #pragma unroll
        for (int n = 0; n < 16; ++n){
            bf16x8 bfr = *(const bf16x8*)(w1t + (size_t)(n*16 + r)*KP + kk*32 + g*8);
            acc[n] = __builtin_amdgcn_mfma_f32_16x16x32_bf16(a, bfr, acc[n], 0, 0, 0);
        }
    }
    #pragma unroll
    for (int n = 0; n < 16; ++n){
        float bv = bias[n*16 + r];
        #pragma unroll
        for (int j = 0; j < 4; ++j){
            int row = row0 + g*4 + j;   // C: col=lane&15, row=(lane>>4)*4+reg
            out[(size_t)row*DH + n*16 + r] = f2bf(acc[n][j] + bv);
        }
    }
}

// ---------------- GEMM2: bf16 MFMA 16x16x32; A=h (m,k), B=w2t (n,k) ----------------
__global__ __launch_bounds__(256) void k_gemm2(const unsigned short* __restrict__ h,
                                               const unsigned short* __restrict__ w2t,
                                               const float* __restrict__ bias,
                                               unsigned short* __restrict__ out, int M){
    const int wave = threadIdx.x >> 6;
    const int lane = threadIdx.x & 63;
    const int row0 = (blockIdx.x*4 + wave) * 16;
    if (row0 >= M) return;
    const int r = lane & 15;
    const int g = lane >> 4;
    f32x4 acc[16];
    #pragma unroll
    for (int n = 0; n < 16; ++n) acc[n] = (f32x4){0.f,0.f,0.f,0.f};
    #pragma unroll
    for (int kk = 0; kk < DH/32; ++kk){
        const int k0 = kk*32;
        bf16x8 a = *(const bf16x8*)(h + (size_t)(row0 + r)*DH + k0 + g*8);
        #pragma unroll
        for (int n = 0; n < 16; ++n){
            bf16x8 bfr = *(const bf16x8*)(w2t + (size_t)(n*16 + r)*DH + k0 + g*8);
            acc[n] = __builtin_amdgcn_mfma_f32_16x16x32_bf16(a, bfr, acc[n], 0, 0, 0);
        }
    }
    #pragma unroll
    for (int n = 0; n < 16; ++n){
        float bv = bias[n*16 + r];
        #pragma unroll
        for (int j = 0; j < 4; ++j){
            int row = row0 + g*4 + j;
            out[(size_t)row*DH + n*16 + r] = f2bf(acc[n][j] + bv);
        }
    }
}

// 8 independent gathers per step: break the dependent-load chain (MLP x8)
#define GATHER_ACC(U) \
    t0 += bf2f((U).x); t1 += bf2f((U).y); t2 += bf2f((U).z); t3 += bf2f((U).w);

// ---------------- SPMM layer1 (gather by dst-CSR, fused LeakyReLU) ----------------
__global__ __launch_bounds__(256) void k_spmm1(const unsigned short* __restrict__ feat,
                                               const int* __restrict__ row_start,
                                               const int* __restrict__ row_end,
                                               const unsigned short* __restrict__ colS,
                                               const float* __restrict__ att,
                                               unsigned short* __restrict__ out){
    int row = __builtin_amdgcn_readfirstlane(blockIdx.x*4 + (threadIdx.x >> 6));
    int lane = threadIdx.x & 63;
    if (row >= NN) return;
    const size_t loff = (size_t)lane*4;
    float a0=0.f, a1=0.f, a2=0.f, a3=0.f;
    #pragma unroll
    for (int i = 0; i < NRELS; ++i){
        const int s0 = row_start[i*NN + row];
        const int s1 = row_end[i*NN + row];
        const int n = s1 - s0;
        if (n <= 0) continue;
        float t0=0.f, t1=0.f, t2=0.f, t3=0.f;
        int slot = s0;
        for (; slot + 8 <= s1; slot += 8){
            int c0 = colS[slot+0], c1 = colS[slot+1], c2 = colS[slot+2], c3 = colS[slot+3];
            int c4 = colS[slot+4], c5 = colS[slot+5], c6 = colS[slot+6], c7 = colS[slot+7];
            ushort4 u0 = *(const ushort4*)(feat + (size_t)c0*DH + loff);
            ushort4 u1 = *(const ushort4*)(feat + (size_t)c1*DH + loff);
            ushort4 u2 = *(const ushort4*)(feat + (size_t)c2*DH + loff);
            ushort4 u3 = *(const ushort4*)(feat + (size_t)c3*DH + loff);
            ushort4 u4 = *(const ushort4*)(feat + (size_t)c4*DH + loff);
            ushort4 u5 = *(const ushort4*)(feat + (size_t)c5*DH + loff);
            ushort4 u6 = *(const ushort4*)(feat + (size_t)c6*DH + loff);
            ushort4 u7 = *(const ushort4*)(feat + (size_t)c7*DH + loff);
            GATHER_ACC(u0) GATHER_ACC(u1) GATHER_ACC(u2) GATHER_ACC(u3)
            GATHER_ACC(u4) GATHER_ACC(u5) GATHER_ACC(u6) GATHER_ACC(u7)
        }
        for (; slot < s1; ++slot){
            int c = colS[slot];
            ushort4 u = *(const ushort4*)(feat + (size_t)c*DH + loff);
            GATHER_ACC(u)
        }
        float v = att[i] / (float)n;   // = att[i] * (1/indeg)
        a0 += v*t0; a1 += v*t1; a2 += v*t2; a3 += v*t3;
    }
    a0 = a0 > 0.f ? a0 : 0.2f*a0;
    a1 = a1 > 0.f ? a1 : 0.2f*a1;
    a2 = a2 > 0.f ? a2 : 0.2f*a2;
    a3 = a3 > 0.f ? a3 : 0.2f*a3;
    ushort4 o; o.x = f2bf(a0); o.y = f2bf(a1); o.z = f2bf(a2); o.w = f2bf(a3);
    *(ushort4*)(&out[(size_t)row*DH + loff]) = o;
}

// ---------------- SPMM layer2 (gather by src-CSR, fused L2 normalize) ----------------
__global__ __launch_bounds__(256) void k_spmm2(const unsigned short* __restrict__ feat,
                                               const int* __restrict__ row_start,
                                               const int* __restrict__ row_end,
                                               const unsigned short* __restrict__ colS,
                                               const float* __restrict__ att,
                                               float* __restrict__ out){
    int row = __builtin_amdgcn_readfirstlane(blockIdx.x*4 + (threadIdx.x >> 6));
    int lane = threadIdx.x & 63;
    if (row >= NN) return;
    const size_t loff = (size_t)lane*4;
    float a0=0.f, a1=0.f, a2=0.f, a3=0.f;
    #pragma unroll
    for (int i = 0; i < NRELS; ++i){
        const int a = NRELS + i;
        const int s0 = row_start[a*NN + row];
        const int s1 = row_end[a*NN + row];
        const int n = s1 - s0;
        if (n <= 0) continue;
        float t0=0.f, t1=0.f, t2=0.f, t3=0.f;
        int slot = s0;
        for (; slot + 8 <= s1; slot += 8){
            int c0 = colS[slot+0], c1 = colS[slot+1], c2 = colS[slot+2], c3 = colS[slot+3];
            int c4 = colS[slot+4], c5 = colS[slot+5], c6 = colS[slot+6], c7 = colS[slot+7];
            ushort4 u0 = *(const ushort4*)(feat + (size_t)c0*DH + loff);
            ushort4 u1 = *(const ushort4*)(feat + (size_t)c1*DH + loff);
            ushort4 u2 = *(const ushort4*)(feat + (size_t)c2*DH + loff);
            ushort4 u3 = *(const ushort4*)(feat + (size_t)c3*DH + loff);
            ushort4 u4 = *(const ushort4*)(feat + (size_t)c4*DH + loff);
            ushort4 u5 = *(const ushort4*)(feat + (size_t)c5*DH + loff);
            ushort4 u6 = *(const ushort4*)(feat + (size_t)c6*DH + loff);
            ushort4 u7 = *(const ushort4*)(feat + (size_t)c7*DH + loff);
            GATHER_ACC(u0) GATHER_ACC(u1) GATHER_ACC(u2) GATHER_ACC(u3)
            GATHER_ACC(u4) GATHER_ACC(u5) GATHER_ACC(u6) GATHER_ACC(u7)
        }
        for (; slot < s1; ++slot){
            int c = colS[slot];
            ushort4 u = *(const ushort4*)(feat + (size_t)c*DH + loff);
            GATHER_ACC(u)
        }
        float v = att[a] / (float)n;   // = att2[i] * (1/outdeg)
        a0 += v*t0; a1 += v*t1; a2 += v*t2; a3 += v*t3;
    }
    float ss = a0*a0 + a1*a1 + a2*a2 + a3*a3;
    #pragma unroll
    for (int off = 32; off > 0; off >>= 1) ss += __shfl_xor(ss, off);
    float scale = 1.0f / fmaxf(sqrtf(ss), 1e-12f);
    float4 o; o.x = a0*scale; o.y = a1*scale; o.z = a2*scale; o.w = a3*scale;
    *(float4*)(&out[(size_t)row*DH + loff]) = o;
}

extern "C" void kernel_launch(void* const* d_in, const int* in_sizes, int n_in,
                              void* d_out, int out_size, void* d_ws, size_t ws_size,
                              hipStream_t stream){
    const float* x      = (const float*)d_in[0];
    const float* w1     = (const float*)d_in[1];
    const float* b1     = (const float*)d_in[2];
    const float* w2     = (const float*)d_in[3];
    const float* b2     = (const float*)d_in[4];
    const float* a_att  = (const float*)d_in[5];
    const float* r_att  = (const float*)d_in[6];
    const int*   src    = (const int*)d_in[7];
    const int*   dst    = (const int*)d_in[8];
    float* out = (float*)d_out;

    char* ws = (char*)d_ws;
    size_t off = 0;
    auto take = [&](size_t bytes)->char*{
        char* p = ws + off;
        off = (off + bytes + 255) & ~(size_t)255;
        return p;
    };
    float*          att         = (float*)take(6*sizeof(float));
    unsigned short* sbuf        = (unsigned short*)take((size_t)NN*DH*2); // s, later s2
    unsigned short* hbuf        = (unsigned short*)take((size_t)NN*DH*2); // h
    unsigned short* w1t         = (unsigned short*)take((size_t)DH*KP*2);
    unsigned short* w2t         = (unsigned short*)take((size_t)DH*DH*2);
    int*            bcur        = (int*)take((size_t)NBT*PAD*4);
    int*            row_start   = (int*)take((size_t)6*NN*4);
    int*            row_end     = (int*)take((size_t)6*NN*4);
    unsigned int*   bucketbuf   = (unsigned int*)take((size_t)NBT*CAP*4);
    unsigned short* colS        = (unsigned short*)take((size_t)NBT*CAP*2);
    (void)ws_size; (void)in_sizes; (void)n_in; (void)out_size;

    k_att<<<1, 64, 0, stream>>>(a_att, r_att, att);
    k_w1t<<<(DH*KP + 255)/256, 256, 0, stream>>>(w1, w1t);
    k_w2t<<<(DH*DH + 255)/256, 256, 0, stream>>>(w2, w2t);
    k_binit<<<(NBT + 255)/256, 256, 0, stream>>>(bcur);

    dim3 sgrid((NE + CHUNK - 1)/CHUNK, NRELS);
    k_bscatter_agg<<<sgrid, 256, 0, stream>>>(src, dst, bcur, bucketbuf);
    k_bfinal<<<NBT, 256, 0, stream>>>(bucketbuf, bcur, row_start, row_end, colS);

    // layer 1: s = x@w1+b1 (MFMA) ; h = leaky(sum_i att[i]*spmm_i(s))
    k_gemm1<<<(NN/16 + 3)/4, 256, 0, stream>>>(x, w1t, b1, sbuf, NN);
    k_spmm1<<<(NN + 3)/4, 256, 0, stream>>>(sbuf, row_start, row_end, colS, att, hbuf);

    // layer 2: s2 = h@w2+b2 (MFMA) ; out = normalize(sum att2*spmm(s2))
    k_gemm2<<<(NN/16 + 3)/4, 256, 0, stream>>>(hbuf, w2t, b2, sbuf, NN);
    k_spmm2<<<(NN + 3)/4, 256, 0, stream>>>(sbuf, row_start, row_end, colS, att, out);
}

// Round 6
// 690.571 us; speedup vs baseline: 2.4725x; 1.0070x over previous
//
#include <hip/hip_runtime.h>
#include <stdint.h>

#define NN 50000      // nodes
#define NRELS 3       // relations
#define NE 800000     // edges per relation
#define DIN 300
#define KP 320        // DIN padded to multiple of 32
#define DH 256
#define NBUK 196      // ceil(NN/256) row-buckets per CSR set
#define NBT (6*NBUK)  // 1176 scatter buckets (layer x rel x rowbucket)
#define PAD 16        // ints per bucket cursor (one 64B line)
#define CAP 5120      // slots per scatter bucket (mean 4096 + 16 sigma)
#define MCAP (3*CAP)  // merged colS region per (layer,rowbucket)
#define CHUNK 4096    // edges per scatter block
#define NLB 392       // local buckets per scatter block (2 sets x 196)

typedef __attribute__((ext_vector_type(8))) short bf16x8;
typedef __attribute__((ext_vector_type(4))) float f32x4;

__device__ __forceinline__ float bf2f(unsigned short u){
    union { unsigned int i; float f; } v; v.i = ((unsigned int)u) << 16; return v.f;
}
__device__ __forceinline__ unsigned short f2bf(float f){
    union { float f; unsigned int i; } v; v.f = f;
    return (unsigned short)((v.i + 0x7FFFu + ((v.i >> 16) & 1u)) >> 16);
}

// ---------------- fused prep: w1t | w2t | binit | att ----------------
__global__ void k_prep(const float* __restrict__ w1, const float* __restrict__ w2,
                       const float* __restrict__ a_att, const float* __restrict__ r_att,
                       unsigned short* __restrict__ w1t, unsigned short* __restrict__ w2t,
                       int* __restrict__ bcur, float* __restrict__ att){
    int b = blockIdx.x, tid = threadIdx.x;
    if (b < 320){                       // w1t[n][k], zero-padded k>=DIN
        int idx = b*256 + tid;
        int n = idx / KP, k = idx % KP;
        w1t[idx] = (k < DIN) ? f2bf(w1[(size_t)k*DH + n]) : 0;
    } else if (b < 576){                // w2t[n][k]
        int idx = (b-320)*256 + tid;
        int n = idx >> 8, k = idx & 255;
        w2t[idx] = f2bf(w2[k*DH + n]);
    } else if (b < 581){                // bucket cursors
        int i = (b-576)*256 + tid;
        if (i < NBT) bcur[i*PAD] = i*CAP;
    } else if (tid == 0){               // attention softmax
        float m = fmaxf(a_att[0], fmaxf(a_att[1], a_att[2]));
        float e0 = expf(a_att[0]-m), e1 = expf(a_att[1]-m), e2 = expf(a_att[2]-m);
        float s = e0+e1+e2;
        att[0]=e0/s; att[1]=e1/s; att[2]=e2/s;
        m = fmaxf(r_att[0], fmaxf(r_att[1], r_att[2]));
        e0 = expf(r_att[0]-m); e1 = expf(r_att[1]-m); e2 = expf(r_att[2]-m);
        s = e0+e1+e2;
        att[3]=e0/s; att[4]=e1/s; att[5]=e2/s;
    }
}

// ---------------- block-aggregated scatter (entries: row<<16 | col) ----------------
__global__ __launch_bounds__(256) void k_bscatter_agg(const int* __restrict__ src,
                                                      const int* __restrict__ dst,
                                                      int* __restrict__ bcur,
                                                      unsigned int* __restrict__ bucketbuf){
    __shared__ unsigned int ledge[2*CHUNK];     // 32 KB
    __shared__ unsigned short lbid[2*CHUNK];    // 16 KB
    __shared__ int lhist[448];                  // padded to 64*7
    __shared__ int lstart[NLB];
    __shared__ int gbase[NLB];
    __shared__ int glim[NLB];
    const int rel = blockIdx.y;
    const int e0 = blockIdx.x*CHUNK;
    const int tid = threadIdx.x;
    for (int i = tid; i < 448; i += 256) lhist[i] = 0;
    __syncthreads();
    int sv[16], dv[16];
    #pragma unroll
    for (int j = 0; j < 16; ++j){
        int e = e0 + j*256 + tid;
        if (e < NE){
            sv[j] = src[(size_t)rel*NE + e];
            dv[j] = dst[(size_t)rel*NE + e];
            atomicAdd(&lhist[dv[j] >> 8], 1);          // layer1 bucket (row=dst)
            atomicAdd(&lhist[196 + (sv[j] >> 8)], 1);  // layer2 bucket (row=src)
        } else sv[j] = -1;
    }
    __syncthreads();
    if (tid < 64){
        int base = tid*7, s = 0, tmp[7];
        #pragma unroll
        for (int j = 0; j < 7; ++j){ tmp[j] = s; s += lhist[base+j]; }
        int run = s;
        #pragma unroll
        for (int off_ = 1; off_ < 64; off_ <<= 1){
            int t = __shfl_up(run, off_);
            if (tid >= off_) run += t;
        }
        int excl = run - s;
        #pragma unroll
        for (int j = 0; j < 7; ++j) lhist[base+j] = tmp[j] + excl;
    }
    __syncthreads();
    for (int i = tid; i < NLB; i += 256) lstart[i] = lhist[i];
    __syncthreads();
    #pragma unroll
    for (int j = 0; j < 16; ++j){
        if (sv[j] >= 0){
            int lb = dv[j] >> 8;
            int pos = atomicAdd(&lhist[lb], 1);
            ledge[pos] = ((unsigned)dv[j] << 16) | (unsigned)sv[j];
            lbid[pos] = (unsigned short)lb;
            lb = 196 + (sv[j] >> 8);
            pos = atomicAdd(&lhist[lb], 1);
            ledge[pos] = ((unsigned)sv[j] << 16) | (unsigned)dv[j];
            lbid[pos] = (unsigned short)lb;
        }
    }
    __syncthreads();
    for (int lb = tid; lb < NLB; lb += 256){
        int cnt = lhist[lb] - lstart[lb];
        if (cnt > 0){
            int gb = (lb < 196) ? (rel*NBUK + lb) : ((NRELS+rel)*NBUK + lb - 196);
            int base = atomicAdd(&bcur[gb*PAD], cnt);
            gbase[lb] = base;
            glim[lb]  = min(base + cnt, gb*CAP + CAP);  // overflow clamp
        }
    }
    __syncthreads();
    const int total = min(NE - e0, CHUNK)*2;
    for (int i = tid; i < total; i += 256){
        int lb = lbid[i];
        int dest = gbase[lb] + (i - lstart[lb]);
        if (dest < glim[lb]) bucketbuf[dest] = ledge[i];
    }
}

// ------- merged finalize: 392 blocks, each merges 3 rel-buckets of one row-range -------
// output: colS region (layer,bu) at (a2*NBUK+bu)*MCAP, rows packed rel-major;
//         rowmeta[a2*NN+row] = {s0, s1, s2, end} (global colS indices)
__global__ __launch_bounds__(256) void k_bfinal(const unsigned int* __restrict__ bucketbuf,
                                                const int* __restrict__ bcur,
                                                int4* __restrict__ rowmeta,
                                                unsigned short* __restrict__ colS){
    __shared__ int lhist[1024];
    __shared__ int lcur[1024];
    __shared__ int wtot[4];
    const int b = blockIdx.x;          // 0..391
    const int a2 = b / NBUK, bu = b % NBUK;
    const int row0 = bu << 8;
    const int obase = b * MCAP;
    const int tid = threadIdx.x;
    for (int i = tid; i < 1024; i += 256) lhist[i] = 0;
    __syncthreads();
    int srcb[3], scnt[3];
    #pragma unroll
    for (int i = 0; i < 3; ++i){
        int gb = (a2*NRELS + i)*NBUK + bu;
        srcb[i] = gb*CAP;
        scnt[i] = min(bcur[gb*PAD] - srcb[i], CAP);
    }
    #pragma unroll
    for (int i = 0; i < 3; ++i){
        for (int j = tid; j < scnt[i]; j += 256){
            unsigned p = bucketbuf[srcb[i] + j];
            atomicAdd(&lhist[(((p >> 16) & 255) << 2) | i], 1);
        }
    }
    __syncthreads();
    // exclusive scan over 1024 bins; thread t owns bins 4t..4t+3 (bin 4t+3 unused = 0)
    int c0 = lhist[4*tid], c1 = lhist[4*tid+1], c2 = lhist[4*tid+2];
    int tsum = c0 + c1 + c2;
    int lane = tid & 63, wv = tid >> 6;
    int incl = tsum;
    #pragma unroll
    for (int off_ = 1; off_ < 64; off_ <<= 1){
        int t = __shfl_up(incl, off_);
        if (lane >= off_) incl += t;
    }
    if (lane == 63) wtot[wv] = incl;
    __syncthreads();
    int woff = 0;
    #pragma unroll
    for (int w = 0; w < 4; ++w) woff += (w < wv) ? wtot[w] : 0;
    int toff = woff + incl - tsum;
    lhist[4*tid]   = toff;
    lhist[4*tid+1] = toff + c0;
    lhist[4*tid+2] = toff + c0 + c1;
    lcur[4*tid]    = toff;
    lcur[4*tid+1]  = toff + c0;
    lcur[4*tid+2]  = toff + c0 + c1;
    int rows = NN - row0; if (rows > 256) rows = 256;
    if (tid < rows){
        int4 m;
        m.x = obase + toff;
        m.y = obase + toff + c0;
        m.z = obase + toff + c0 + c1;
        m.w = obase + toff + c0 + c1 + c2;
        rowmeta[a2*NN + row0 + tid] = m;
    }
    __syncthreads();
    #pragma unroll
    for (int i = 0; i < 3; ++i){
        for (int j = tid; j < scnt[i]; j += 256){
            unsigned p = bucketbuf[srcb[i] + j];
            int pos = atomicAdd(&lcur[(((p >> 16) & 255) << 2) | i], 1);
            colS[obase + pos] = (unsigned short)(p & 0xFFFFu);
        }
    }
}

// ---------------- GEMM1: MFMA bf16; A=x (f32, converted inline), B=w1t ----------------
__global__ __launch_bounds__(256) void k_gemm1(const float* __restrict__ x,
                                               const unsigned short* __restrict__ w1t,
                                               const float* __restrict__ bias,
                                               unsigned short* __restrict__ out, int M){
    const int wave = threadIdx.x >> 6;
    const int lane = threadIdx.x & 63;
    const int row0 = (blockIdx.x*4 + wave) * 16;
    if (row0 >= M) return;
    const int r = lane & 15;
    const int g = lane >> 4;
    const float* xrow = x + (size_t)(row0 + r)*DIN;
    f32x4 acc[16];
    #pragma unroll
    for (int n = 0; n < 16; ++n) acc[n] = (f32x4){0.f,0.f,0.f,0.f};
    #pragma unroll
    for (int kk = 0; kk < KP/32; ++kk){
        const int k0 = kk*32 + g*8;
        bf16x8 a;
        if (kk < 9){
            float4 xa = *(const float4*)(xrow + k0);
            float4 xb = *(const float4*)(xrow + k0 + 4);
            a[0]=(short)f2bf(xa.x); a[1]=(short)f2bf(xa.y);
            a[2]=(short)f2bf(xa.z); a[3]=(short)f2bf(xa.w);
            a[4]=(short)f2bf(xb.x); a[5]=(short)f2bf(xb.y);
            a[6]=(short)f2bf(xb.z); a[7]=(short)f2bf(xb.w);
        } else {
            #pragma unroll
            for (int j = 0; j < 8; ++j){
                int k = k0 + j;
                a[j] = (short)((k < DIN) ? f2bf(xrow[k]) : 0);
            }
        }
        #pragma unroll
        for (int n = 0; n < 16; ++n){
            bf16x8 bfr = *(const bf16x8*)(w1t + (size_t)(n*16 + r)*KP + kk*32 + g*8);
            acc[n] = __builtin_amdgcn_mfma_f32_16x16x32_bf16(a, bfr, acc[n], 0, 0, 0);
        }
    }
    #pragma unroll
    for (int n = 0; n < 16; ++n){
        float bv = bias[n*16 + r];
        #pragma unroll
        for (int j = 0; j < 4; ++j){
            int row = row0 + g*4 + j;   // C: col=lane&15, row=(lane>>4)*4+reg
            out[(size_t)row*DH + n*16 + r] = f2bf(acc[n][j] + bv);
        }
    }
}

// ---------------- GEMM2: bf16 MFMA 16x16x32; A=h (m,k), B=w2t (n,k) ----------------
__global__ __launch_bounds__(256) void k_gemm2(const unsigned short* __restrict__ h,
                                               const unsigned short* __restrict__ w2t,
                                               const float* __restrict__ bias,
                                               unsigned short* __restrict__ out, int M){
    const int wave = threadIdx.x >> 6;
    const int lane = threadIdx.x & 63;
    const int row0 = (blockIdx.x*4 + wave) * 16;
    if (row0 >= M) return;
    const int r = lane & 15;
    const int g = lane >> 4;
    f32x4 acc[16];
    #pragma unroll
    for (int n = 0; n < 16; ++n) acc[n] = (f32x4){0.f,0.f,0.f,0.f};
    #pragma unroll
    for (int kk = 0; kk < DH/32; ++kk){
        const int k0 = kk*32;
        bf16x8 a = *(const bf16x8*)(h + (size_t)(row0 + r)*DH + k0 + g*8);
        #pragma unroll
        for (int n = 0; n < 16; ++n){
            bf16x8 bfr = *(const bf16x8*)(w2t + (size_t)(n*16 + r)*DH + k0 + g*8);
            acc[n] = __builtin_amdgcn_mfma_f32_16x16x32_bf16(a, bfr, acc[n], 0, 0, 0);
        }
    }
    #pragma unroll
    for (int n = 0; n < 16; ++n){
        float bv = bias[n*16 + r];
        #pragma unroll
        for (int j = 0; j < 4; ++j){
            int row = row0 + g*4 + j;
            out[(size_t)row*DH + n*16 + r] = f2bf(acc[n][j] + bv);
        }
    }
}

// -------- SPMM core: one flattened batched loop over all 3 relation segments --------
// every batch keeps 8 gathers in flight (tail uses clamped dummy slots, val=0)
#define SPMM_BODY(M_, ACCUM)                                                         \
    const int e = M_.w;                                                              \
    int slot = M_.x;                                                                 \
    if (e > slot){                                                                   \
        const int e1 = e - 1;                                                        \
        for (; slot < e; slot += 8){                                                 \
            int cc[8]; float vv[8];                                                  \
            _Pragma("unroll")                                                        \
            for (int j = 0; j < 8; ++j){                                             \
                int sj = slot + j;                                                   \
                cc[j] = colS[min(sj, e1)];                                           \
                float v = (sj < M_.y) ? v0 : ((sj < M_.z) ? v1 : v2);                \
                vv[j] = (sj < e) ? v : 0.f;                                          \
            }                                                                        \
            _Pragma("unroll")                                                        \
            for (int j = 0; j < 8; ++j){                                             \
                ushort4 u = *(const ushort4*)(feat + (size_t)cc[j]*DH + loff);       \
                ACCUM(u, vv[j])                                                      \
            }                                                                        \
        }                                                                            \
    }
#define ACC4(U, V) \
    a0 = fmaf(V, bf2f((U).x), a0); a1 = fmaf(V, bf2f((U).y), a1); \
    a2 = fmaf(V, bf2f((U).z), a2); a3 = fmaf(V, bf2f((U).w), a3);

// ---------------- SPMM layer1 (fused LeakyReLU) ----------------
__global__ __launch_bounds__(256) void k_spmm1(const unsigned short* __restrict__ feat,
                                               const int4* __restrict__ rowmeta,
                                               const unsigned short* __restrict__ colS,
                                               const float* __restrict__ att,
                                               unsigned short* __restrict__ out){
    int row = __builtin_amdgcn_readfirstlane(blockIdx.x*4 + (threadIdx.x >> 6));
    int lane = threadIdx.x & 63;
    if (row >= NN) return;
    const size_t loff = (size_t)lane*4;
    int4 m = rowmeta[row];
    float v0 = att[0] / (float)max(m.y - m.x, 1);
    float v1 = att[1] / (float)max(m.z - m.y, 1);
    float v2 = att[2] / (float)max(m.w - m.z, 1);
    float a0=0.f, a1=0.f, a2=0.f, a3=0.f;
    SPMM_BODY(m, ACC4)
    a0 = a0 > 0.f ? a0 : 0.2f*a0;
    a1 = a1 > 0.f ? a1 : 0.2f*a1;
    a2 = a2 > 0.f ? a2 : 0.2f*a2;
    a3 = a3 > 0.f ? a3 : 0.2f*a3;
    ushort4 o; o.x = f2bf(a0); o.y = f2bf(a1); o.z = f2bf(a2); o.w = f2bf(a3);
    *(ushort4*)(&out[(size_t)row*DH + loff]) = o;
}

// ---------------- SPMM layer2 (fused L2 normalize) ----------------
__global__ __launch_bounds__(256) void k_spmm2(const unsigned short* __restrict__ feat,
                                               const int4* __restrict__ rowmeta,
                                               const unsigned short* __restrict__ colS,
                                               const float* __restrict__ att,
                                               float* __restrict__ out){
    int row = __builtin_amdgcn_readfirstlane(blockIdx.x*4 + (threadIdx.x >> 6));
    int lane = threadIdx.x & 63;
    if (row >= NN) return;
    const size_t loff = (size_t)lane*4;
    int4 m = rowmeta[NN + row];
    float v0 = att[3] / (float)max(m.y - m.x, 1);
    float v1 = att[4] / (float)max(m.z - m.y, 1);
    float v2 = att[5] / (float)max(m.w - m.z, 1);
    float a0=0.f, a1=0.f, a2=0.f, a3=0.f;
    SPMM_BODY(m, ACC4)
    float ss = a0*a0 + a1*a1 + a2*a2 + a3*a3;
    #pragma unroll
    for (int off = 32; off > 0; off >>= 1) ss += __shfl_xor(ss, off);
    float scale = 1.0f / fmaxf(sqrtf(ss), 1e-12f);
    float4 o; o.x = a0*scale; o.y = a1*scale; o.z = a2*scale; o.w = a3*scale;
    *(float4*)(&out[(size_t)row*DH + loff]) = o;
}

extern "C" void kernel_launch(void* const* d_in, const int* in_sizes, int n_in,
                              void* d_out, int out_size, void* d_ws, size_t ws_size,
                              hipStream_t stream){
    const float* x      = (const float*)d_in[0];
    const float* w1     = (const float*)d_in[1];
    const float* b1     = (const float*)d_in[2];
    const float* w2     = (const float*)d_in[3];
    const float* b2     = (const float*)d_in[4];
    const float* a_att  = (const float*)d_in[5];
    const float* r_att  = (const float*)d_in[6];
    const int*   src    = (const int*)d_in[7];
    const int*   dst    = (const int*)d_in[8];
    float* out = (float*)d_out;

    char* ws = (char*)d_ws;
    size_t off = 0;
    auto take = [&](size_t bytes)->char*{
        char* p = ws + off;
        off = (off + bytes + 255) & ~(size_t)255;
        return p;
    };
    float*          att         = (float*)take(6*sizeof(float));
    unsigned short* sbuf        = (unsigned short*)take((size_t)NN*DH*2); // s, later s2
    unsigned short* hbuf        = (unsigned short*)take((size_t)NN*DH*2); // h
    unsigned short* w1t         = (unsigned short*)take((size_t)DH*KP*2);
    unsigned short* w2t         = (unsigned short*)take((size_t)DH*DH*2);
    int*            bcur        = (int*)take((size_t)NBT*PAD*4);
    int4*           rowmeta     = (int4*)take((size_t)2*NN*16);
    unsigned int*   bucketbuf   = (unsigned int*)take((size_t)NBT*CAP*4);
    unsigned short* colS        = (unsigned short*)take((size_t)2*NBUK*MCAP*2);
    (void)ws_size; (void)in_sizes; (void)n_in; (void)out_size;

    k_prep<<<582, 256, 0, stream>>>(w1, w2, a_att, r_att, w1t, w2t, bcur, att);

    dim3 sgrid((NE + CHUNK - 1)/CHUNK, NRELS);
    k_bscatter_agg<<<sgrid, 256, 0, stream>>>(src, dst, bcur, bucketbuf);
    k_bfinal<<<2*NBUK, 256, 0, stream>>>(bucketbuf, bcur, rowmeta, colS);

    // layer 1: s = x@w1+b1 (MFMA) ; h = leaky(sum_i att[i]*spmm_i(s))
    k_gemm1<<<(NN/16 + 3)/4, 256, 0, stream>>>(x, w1t, b1, sbuf, NN);
    k_spmm1<<<(NN + 3)/4, 256, 0, stream>>>(sbuf, rowmeta, colS, att, hbuf);

    // layer 2: s2 = h@w2+b2 (MFMA) ; out = normalize(sum att2*spmm(s2))
    k_gemm2<<<(NN/16 + 3)/4, 256, 0, stream>>>(hbuf, w2t, b2, sbuf, NN);
    k_spmm2<<<(NN + 3)/4, 256, 0, stream>>>(sbuf, rowmeta, colS, att, out);
}